// Round 6
// baseline (346.382 us; speedup 1.0000x reference)
//
#include <hip/hip_runtime.h>
#include <hip/hip_bf16.h>
#include <stdint.h>

#define IN_FEATS 128
#define HID 256

typedef __bf16   bf16x8 __attribute__((ext_vector_type(8)));
typedef float    f32x4  __attribute__((ext_vector_type(4)));
typedef _Float16 h2     __attribute__((ext_vector_type(2)));
typedef _Float16 h8     __attribute__((ext_vector_type(8)));

// ---------------- Kernel 0: pack W1 -> MFMA-fragment bf16, W2 -> fp16 ----------
// W1P[((which*4+ks)*16 + nblk)*64 + lane][j] = bf16( W1[which*128+ks*32+(lane>>4)*8+j][nblk*16+(lane&15)] )
__global__ void k_prep(const float* __restrict__ W1, const float* __restrict__ W2,
                       __bf16* __restrict__ W1P, _Float16* __restrict__ W2H) {
    int t = blockIdx.x * 256 + threadIdx.x;   // 33 blocks = 8448 threads
    if (t < 8192) {
        int lane  = t & 63;
        int nblk  = (t >> 6) & 15;
        int ks    = (t >> 10) & 3;
        int which = (t >> 12) & 1;
        int qr = lane & 15, qg = lane >> 4;
        int n  = nblk * 16 + qr;
        int k0 = which * 128 + ks * 32 + qg * 8;
        bf16x8 v;
#pragma unroll
        for (int j = 0; j < 8; ++j)
            v[j] = (__bf16)W1[(size_t)(k0 + j) * HID + n];
        *(bf16x8*)(W1P + (size_t)t * 8) = v;
    } else {
        int i = t - 8192;
        if (i < HID) W2H[i] = (_Float16)W2[i];
    }
}

// ---------------- Kernel A: node projections (fp32 in, fp16 out) ---------------
// P_src[n,256] = h_src[n,:] @ W1[0:128,:] + b1   (blockIdx.y == 0)
// P_dst[n,256] = h_dst[n,:] @ W1[128:256,:]      (blockIdx.y == 1)
__global__ __launch_bounds__(256) void k_proj(
    const float* __restrict__ hs, const float* __restrict__ hd,
    const __bf16* __restrict__ W1P, const float* __restrict__ b1,
    _Float16* __restrict__ Ps, _Float16* __restrict__ Pd)
{
    const int which = blockIdx.y;
    const float* __restrict__ h = which ? hd : hs;
    _Float16* __restrict__ P = which ? Pd : Ps;

    const int lane = threadIdx.x & 63;
    const int w    = threadIdx.x >> 6;   // wave 0..3
    const int n0   = w * 64;
    const int node0 = blockIdx.x * 32;
    const int qr = lane & 15;
    const int qg = lane >> 4;
    const bf16x8* __restrict__ W1Pv = (const bf16x8*)W1P;

    f32x4 acc[2][4];
#pragma unroll
    for (int m = 0; m < 2; ++m)
#pragma unroll
        for (int n = 0; n < 4; ++n) acc[m][n] = (f32x4){0.f, 0.f, 0.f, 0.f};

#pragma unroll
    for (int ks = 0; ks < 4; ++ks) {
        const int k0 = ks * 32 + qg * 8;
        bf16x8 a[2];
#pragma unroll
        for (int m = 0; m < 2; ++m) {
            const float* ap = h + (size_t)(node0 + m * 16 + qr) * IN_FEATS + k0;
            float4 f0 = *(const float4*)ap;
            float4 f1 = *(const float4*)(ap + 4);
            bf16x8 t;
            t[0] = (__bf16)f0.x; t[1] = (__bf16)f0.y; t[2] = (__bf16)f0.z; t[3] = (__bf16)f0.w;
            t[4] = (__bf16)f1.x; t[5] = (__bf16)f1.y; t[6] = (__bf16)f1.z; t[7] = (__bf16)f1.w;
            a[m] = t;
        }
#pragma unroll
        for (int n = 0; n < 4; ++n) {
            bf16x8 b = W1Pv[((size_t)(which * 4 + ks) * 16 + w * 4 + n) * 64 + lane];
#pragma unroll
            for (int m = 0; m < 2; ++m)
                acc[m][n] = __builtin_amdgcn_mfma_f32_16x16x32_bf16(a[m], b, acc[m][n], 0, 0, 0);
        }
    }

    // Epilogue: D layout col=lane&15, row=(lane>>4)*4+i (m89-verified).
    // Pack col-pairs (via lane^1 shuffle) into one u32 fp16x2 store.
    const bool even = (qr & 1) == 0;
    const int i0 = even ? 0 : 2;
#pragma unroll
    for (int n = 0; n < 4; ++n) {
        const int col = n0 + n * 16 + qr;
        const float bias = which ? 0.f : b1[col];
#pragma unroll
        for (int m = 0; m < 2; ++m) {
            const int rowb = node0 + m * 16 + qg * 4;
            float v[4], o[4];
#pragma unroll
            for (int i = 0; i < 4; ++i) {
                v[i] = acc[m][n][i] + bias;
                o[i] = __shfl_xor(v[i], 1, 64);
            }
#pragma unroll
            for (int i = 0; i < 2; ++i) {
                const int r = i0 + i;
                auto pk = even ? __builtin_amdgcn_cvt_pkrtz(v[r], o[r])
                               : __builtin_amdgcn_cvt_pkrtz(o[r], v[r]);
                *(unsigned*)(P + (size_t)(rowb + r) * HID + (col & ~1)) =
                    __builtin_bit_cast(unsigned, pk);
            }
        }
    }
}

// ---------------- Kernel B: edge scoring (fp16, v_dot2 path) -------------------
// score[e] = b2 + sum_j relu(Ps[src[e]][j] + Pd[dst[e]][j]) * W2[j]
// Quarter-wave (16 lanes) per edge slot, 2 edges per slot in flight.
__device__ __forceinline__ float dot8f(h8 a, h8 c, h8 w, float acc) {
    h8 r = a + c;                                        // 4x v_pk_add_f16
    r = __builtin_elementwise_max(r, (h8)(_Float16)0.f); // 4x v_pk_max_f16
#pragma unroll
    for (int j = 0; j < 4; ++j) {
        h2 p = {r[2 * j], r[2 * j + 1]};
        h2 q = {w[2 * j], w[2 * j + 1]};
        acc = __builtin_amdgcn_fdot2(p, q, acc, false);  // v_dot2_f32_f16
    }
    return acc;
}

__global__ __launch_bounds__(256) void k_edge(
    const _Float16* __restrict__ Ps, const _Float16* __restrict__ Pd,
    const int* __restrict__ src, const int* __restrict__ dst,
    const _Float16* __restrict__ W2H, const float* __restrict__ b2,
    float* __restrict__ out, int e_beg, int e_end)
{
    const int lane = threadIdx.x & 63;
    const int q = lane & 15;             // element slice
    const int g = lane >> 4;             // edge slot within wave
    const int wave = blockIdx.x * 4 + (threadIdx.x >> 6);
    const int nw = gridDim.x * 4;

    const h8* __restrict__ W2v = (const h8*)W2H;
    const h8 wa0 = W2v[q];          // W2 elems 8q..8q+7
    const h8 wa1 = W2v[16 + q];     // W2 elems 128+8q..
    const float bias = b2[0];

    for (int base = e_beg + wave * 8; base < e_end; base += nw * 8) {
        const int e0 = base + g;
        const int e1 = base + 4 + g;
        const bool v0 = (e0 < e_end), v1 = (e1 < e_end);
        float acc0 = 0.f, acc1 = 0.f;
        if (v0) {
            const h8* ps = (const h8*)(Ps + (size_t)src[e0] * HID);
            const h8* pd = (const h8*)(Pd + (size_t)dst[e0] * HID);
            h8 a0 = ps[q], a1 = ps[16 + q], c0 = pd[q], c1 = pd[16 + q];
            if (v1) {
                const h8* ps1 = (const h8*)(Ps + (size_t)src[e1] * HID);
                const h8* pd1 = (const h8*)(Pd + (size_t)dst[e1] * HID);
                h8 b0 = ps1[q], b1v = ps1[16 + q], d0 = pd1[q], d1 = pd1[16 + q];
                acc0 = dot8f(a0, c0, wa0, acc0);
                acc0 = dot8f(a1, c1, wa1, acc0);
                acc1 = dot8f(b0, d0, wa0, acc1);
                acc1 = dot8f(b1v, d1, wa1, acc1);
            } else {
                acc0 = dot8f(a0, c0, wa0, acc0);
                acc0 = dot8f(a1, c1, wa1, acc0);
            }
        }
#pragma unroll
        for (int m = 1; m < 16; m <<= 1) {
            acc0 += __shfl_xor(acc0, m, 64);
            acc1 += __shfl_xor(acc1, m, 64);
        }
        if (q == 0) {
            if (v0) out[e0] = acc0 + bias;
            if (v1) out[e1] = acc1 + bias;
        }
    }
}

// ---------------- launch -------------------------------------------------------
extern "C" void kernel_launch(void* const* d_in, const int* in_sizes, int n_in,
                              void* d_out, int out_size, void* d_ws, size_t ws_size,
                              hipStream_t stream) {
    const float* h_src = (const float*)d_in[0];
    const float* h_dst = (const float*)d_in[1];
    const int*   src   = (const int*)d_in[2];
    const int*   dst   = (const int*)d_in[3];
    const float* W1    = (const float*)d_in[4];
    const float* b1    = (const float*)d_in[5];
    const float* W2    = (const float*)d_in[6];
    const float* b2    = (const float*)d_in[7];
    float* out = (float*)d_out;

    const int E  = in_sizes[2];
    const int NN = in_sizes[0] / IN_FEATS;   // 100000

    // ws layout: [W1P bf16 64K elems =128KB][W2H fp16 256][pad to 256KB][Ps fp16][Pd fp16]
    __bf16*    W1P = (__bf16*)d_ws;
    _Float16*  W2H = (_Float16*)((char*)d_ws + 131072);
    _Float16*  Ps  = (_Float16*)((char*)d_ws + 262144);
    _Float16*  Pd  = Ps + (size_t)NN * HID;

    k_prep<<<33, 256, 0, stream>>>(W1, W2, W1P, W2H);
    dim3 gA(NN / 32, 2);
    k_proj<<<gA, 256, 0, stream>>>(h_src, h_dst, W1P, b1, Ps, Pd);
    // Two half-range dispatches: same total work; makes k_proj visible in the
    // top-5 profile window next round (its counters are the open question).
    const int Eh = E / 2;
    k_edge<<<2048, 256, 0, stream>>>(Ps, Pd, src, dst, W2H, b2, out, 0, Eh);
    k_edge<<<2048, 256, 0, stream>>>(Ps, Pd, src, dst, W2H, b2, out, Eh, E);
}

// Round 7
// 313.942 us; speedup vs baseline: 1.1033x; 1.1033x over previous
//
#include <hip/hip_runtime.h>
#include <hip/hip_bf16.h>
#include <stdint.h>

#define IN_FEATS 128
#define HID 256
#define BM 64            // nodes per k_proj block
#define LDA 136          // padded LDS row stride (bf16): breaks bank aliasing

typedef __bf16   bf16x4 __attribute__((ext_vector_type(4)));
typedef __bf16   bf16x8 __attribute__((ext_vector_type(8)));
typedef float    f32x4  __attribute__((ext_vector_type(4)));
typedef _Float16 h2     __attribute__((ext_vector_type(2)));
typedef _Float16 h8     __attribute__((ext_vector_type(8)));

// ---------------- Kernel 0: pack W1 -> MFMA-fragment bf16, W2 -> fp16 ----------
// W1P[((which*4+ks)*16 + nblk)*64 + lane][j] = bf16( W1[which*128+ks*32+(lane>>4)*8+j][nblk*16+(lane&15)] )
__global__ void k_prep(const float* __restrict__ W1, const float* __restrict__ W2,
                       __bf16* __restrict__ W1P, _Float16* __restrict__ W2H) {
    int t = blockIdx.x * 256 + threadIdx.x;   // 33 blocks = 8448 threads
    if (t < 8192) {
        int lane  = t & 63;
        int nblk  = (t >> 6) & 15;
        int ks    = (t >> 10) & 3;
        int which = (t >> 12) & 1;
        int qr = lane & 15, qg = lane >> 4;
        int n  = nblk * 16 + qr;
        int k0 = which * 128 + ks * 32 + qg * 8;
        bf16x8 v;
#pragma unroll
        for (int j = 0; j < 8; ++j)
            v[j] = (__bf16)W1[(size_t)(k0 + j) * HID + n];
        *(bf16x8*)(W1P + (size_t)t * 8) = v;
    } else {
        int i = t - 8192;
        if (i < HID) W2H[i] = (_Float16)W2[i];
    }
}

// ---------------- Kernel A: node projections (LDS-staged, fp32 in, fp16 out) ---
// P_src[n,256] = h_src[n,:] @ W1[0:128,:] + b1   (blockIdx.y == 0)
// P_dst[n,256] = h_dst[n,:] @ W1[128:256,:]      (blockIdx.y == 1)
// Block: 64 nodes x 256 cols, 4 waves (wave tile 64x64, acc[4][4]).
// A staged in LDS as bf16 with padded stride; B from L2-resident packed W1P.
__global__ __launch_bounds__(256) void k_proj(
    const float* __restrict__ hs, const float* __restrict__ hd,
    const __bf16* __restrict__ W1P, const float* __restrict__ b1,
    _Float16* __restrict__ Ps, _Float16* __restrict__ Pd, int NN)
{
    __shared__ __bf16 Atile[BM][LDA];

    const int which = blockIdx.y;
    const float* __restrict__ h = which ? hd : hs;
    _Float16* __restrict__ P = which ? Pd : Ps;

    const int lane  = threadIdx.x & 63;
    const int w     = threadIdx.x >> 6;   // wave 0..3 -> col group
    const int n0    = w * 64;
    const int node0 = blockIdx.x * BM;
    const int qr = lane & 15;
    const int qg = lane >> 4;
    const bf16x8* __restrict__ W1Pv = (const bf16x8*)W1P;

    // ---- stage A: 64 rows x 128 fp32 -> bf16 LDS. Chunk g = 16B fp32 piece;
    // instr j covers a contiguous 4KB of h (perfectly coalesced).
    {
        const int t = threadIdx.x;
#pragma unroll
        for (int j = 0; j < 8; ++j) {
            int g   = t + 256 * j;        // 0..2047: 32 chunks per row
            int row = g >> 5;
            int c4  = (g & 31) * 4;       // float offset within row
            int rsrc = node0 + row; if (rsrc > NN - 1) rsrc = NN - 1;
            float4 f = *(const float4*)(h + (size_t)rsrc * IN_FEATS + c4);
            bf16x4 v = { (__bf16)f.x, (__bf16)f.y, (__bf16)f.z, (__bf16)f.w };
            *(bf16x4*)&Atile[row][c4] = v;
        }
    }
    __syncthreads();

    f32x4 acc[4][4];
#pragma unroll
    for (int m = 0; m < 4; ++m)
#pragma unroll
        for (int n = 0; n < 4; ++n) acc[m][n] = (f32x4){0.f, 0.f, 0.f, 0.f};

#pragma unroll
    for (int ks = 0; ks < 4; ++ks) {
        bf16x8 a[4];
#pragma unroll
        for (int m = 0; m < 4; ++m)
            a[m] = *(const bf16x8*)&Atile[m * 16 + qr][ks * 32 + qg * 8];
#pragma unroll
        for (int n = 0; n < 4; ++n) {
            bf16x8 b = W1Pv[((size_t)(which * 4 + ks) * 16 + w * 4 + n) * 64 + lane];
#pragma unroll
            for (int m = 0; m < 4; ++m)
                acc[m][n] = __builtin_amdgcn_mfma_f32_16x16x32_bf16(a[m], b, acc[m][n], 0, 0, 0);
        }
    }

    // ---- epilogue: D layout col=lane&15, row=(lane>>4)*4+i (m89-verified).
    // Pack col-pairs (via lane^1 shuffle) into one u32 fp16x2 store.
    const bool even = (qr & 1) == 0;
    const int i0 = even ? 0 : 2;
#pragma unroll
    for (int n = 0; n < 4; ++n) {
        const int col = n0 + n * 16 + qr;
        const float bias = which ? 0.f : b1[col];
#pragma unroll
        for (int m = 0; m < 4; ++m) {
            const int rowb = m * 16 + qg * 4;
            float v[4], o[4];
#pragma unroll
            for (int i = 0; i < 4; ++i) {
                v[i] = acc[m][n][i] + bias;
                o[i] = __shfl_xor(v[i], 1, 64);
            }
#pragma unroll
            for (int i = 0; i < 2; ++i) {
                const int r = i0 + i;
                if (node0 + rowb + r < NN) {
                    auto pk = even ? __builtin_amdgcn_cvt_pkrtz(v[r], o[r])
                                   : __builtin_amdgcn_cvt_pkrtz(o[r], v[r]);
                    *(unsigned*)(P + (size_t)(node0 + rowb + r) * HID + (col & ~1)) =
                        __builtin_bit_cast(unsigned, pk);
                }
            }
        }
    }
}

// ---------------- Kernel B: edge scoring (fp16, v_dot2 path) -------------------
// score[e] = b2 + sum_j relu(Ps[src[e]][j] + Pd[dst[e]][j]) * W2[j]
// Quarter-wave (16 lanes) per edge slot, 2 edges per slot in flight.
// Fabric-BW-bound (~3.5 TB/s L2-miss service on random lines) — structural.
__device__ __forceinline__ float dot8f(h8 a, h8 c, h8 w, float acc) {
    h8 r = a + c;                                        // 4x v_pk_add_f16
    r = __builtin_elementwise_max(r, (h8)(_Float16)0.f); // 4x v_pk_max_f16
#pragma unroll
    for (int j = 0; j < 4; ++j) {
        h2 p = {r[2 * j], r[2 * j + 1]};
        h2 q = {w[2 * j], w[2 * j + 1]};
        acc = __builtin_amdgcn_fdot2(p, q, acc, false);  // v_dot2_f32_f16
    }
    return acc;
}

__global__ __launch_bounds__(256) void k_edge(
    const _Float16* __restrict__ Ps, const _Float16* __restrict__ Pd,
    const int* __restrict__ src, const int* __restrict__ dst,
    const _Float16* __restrict__ W2H, const float* __restrict__ b2,
    float* __restrict__ out, int e_beg, int e_end)
{
    const int lane = threadIdx.x & 63;
    const int q = lane & 15;             // element slice
    const int g = lane >> 4;             // edge slot within wave
    const int wave = blockIdx.x * 4 + (threadIdx.x >> 6);
    const int nw = gridDim.x * 4;

    const h8* __restrict__ W2v = (const h8*)W2H;
    const h8 wa0 = W2v[q];          // W2 elems 8q..8q+7
    const h8 wa1 = W2v[16 + q];     // W2 elems 128+8q..
    const float bias = b2[0];

    for (int base = e_beg + wave * 8; base < e_end; base += nw * 8) {
        const int e0 = base + g;
        const int e1 = base + 4 + g;
        const bool v0 = (e0 < e_end), v1 = (e1 < e_end);
        float acc0 = 0.f, acc1 = 0.f;
        if (v0) {
            const h8* ps = (const h8*)(Ps + (size_t)src[e0] * HID);
            const h8* pd = (const h8*)(Pd + (size_t)dst[e0] * HID);
            h8 a0 = ps[q], a1 = ps[16 + q], c0 = pd[q], c1 = pd[16 + q];
            if (v1) {
                const h8* ps1 = (const h8*)(Ps + (size_t)src[e1] * HID);
                const h8* pd1 = (const h8*)(Pd + (size_t)dst[e1] * HID);
                h8 b0 = ps1[q], b1v = ps1[16 + q], d0 = pd1[q], d1 = pd1[16 + q];
                acc0 = dot8f(a0, c0, wa0, acc0);
                acc0 = dot8f(a1, c1, wa1, acc0);
                acc1 = dot8f(b0, d0, wa0, acc1);
                acc1 = dot8f(b1v, d1, wa1, acc1);
            } else {
                acc0 = dot8f(a0, c0, wa0, acc0);
                acc0 = dot8f(a1, c1, wa1, acc0);
            }
        }
#pragma unroll
        for (int m = 1; m < 16; m <<= 1) {
            acc0 += __shfl_xor(acc0, m, 64);
            acc1 += __shfl_xor(acc1, m, 64);
        }
        if (q == 0) {
            if (v0) out[e0] = acc0 + bias;
            if (v1) out[e1] = acc1 + bias;
        }
    }
}

// ---------------- launch -------------------------------------------------------
extern "C" void kernel_launch(void* const* d_in, const int* in_sizes, int n_in,
                              void* d_out, int out_size, void* d_ws, size_t ws_size,
                              hipStream_t stream) {
    const float* h_src = (const float*)d_in[0];
    const float* h_dst = (const float*)d_in[1];
    const int*   src   = (const int*)d_in[2];
    const int*   dst   = (const int*)d_in[3];
    const float* W1    = (const float*)d_in[4];
    const float* b1    = (const float*)d_in[5];
    const float* W2    = (const float*)d_in[6];
    const float* b2    = (const float*)d_in[7];
    float* out = (float*)d_out;

    const int E  = in_sizes[2];
    const int NN = in_sizes[0] / IN_FEATS;   // 100000

    // ws layout: [W1P bf16 64K elems =128KB][W2H fp16 256][pad to 256KB][Ps fp16][Pd fp16]
    __bf16*    W1P = (__bf16*)d_ws;
    _Float16*  W2H = (_Float16*)((char*)d_ws + 131072);
    _Float16*  Ps  = (_Float16*)((char*)d_ws + 262144);
    _Float16*  Pd  = Ps + (size_t)NN * HID;

    k_prep<<<33, 256, 0, stream>>>(W1, W2, W1P, W2H);
    dim3 gA((NN + BM - 1) / BM, 2);
    k_proj<<<gA, 256, 0, stream>>>(h_src, h_dst, W1P, b1, Ps, Pd, NN);
    const int Eh = E / 2;
    k_edge<<<2048, 256, 0, stream>>>(Ps, Pd, src, dst, W2H, b2, out, 0, Eh);
    k_edge<<<2048, 256, 0, stream>>>(Ps, Pd, src, dst, W2H, b2, out, Eh, E);
}

// Round 8
// 298.756 us; speedup vs baseline: 1.1594x; 1.0508x over previous
//
#include <hip/hip_runtime.h>
#include <hip/hip_bf16.h>
#include <stdint.h>

#define IN_FEATS 128
#define HID 256
#define BM 64            // nodes per k_proj block
#define LDA 136          // padded LDS row stride (bf16): 272B = 17x16B, keeps
                         // b128 alignment; frag-read starts hit banks 0,4,..,60
                         // -> 2-way (free, m136)

typedef __bf16   bf16x4 __attribute__((ext_vector_type(4)));
typedef __bf16   bf16x8 __attribute__((ext_vector_type(8)));
typedef float    f32x4  __attribute__((ext_vector_type(4)));
typedef _Float16 h2     __attribute__((ext_vector_type(2)));
typedef _Float16 h8     __attribute__((ext_vector_type(8)));

// ---------------- Kernel 0: pack W1 -> MFMA-frag bf16; W2 -> fp16 (PERMUTED) ---
// W1P[((which*4+ks)*16 + nblk)*64 + lane][j] = bf16( W1[which*128+ks*32+(lane>>4)*8+j][nblk*16+(lane&15)] )
// P rows are stored in fragment-native order: new elem pos w*64+qr*4+n holds old
// col w*64+n*16+qr. W2H is permuted to match so k_edge's dot stays aligned.
__global__ void k_prep(const float* __restrict__ W1, const float* __restrict__ W2,
                       __bf16* __restrict__ W1P, _Float16* __restrict__ W2H) {
    int t = blockIdx.x * 256 + threadIdx.x;   // 33 blocks = 8448 threads
    if (t < 8192) {
        int lane  = t & 63;
        int nblk  = (t >> 6) & 15;
        int ks    = (t >> 10) & 3;
        int which = (t >> 12) & 1;
        int qr = lane & 15, qg = lane >> 4;
        int n  = nblk * 16 + qr;
        int k0 = which * 128 + ks * 32 + qg * 8;
        bf16x8 v;
#pragma unroll
        for (int j = 0; j < 8; ++j)
            v[j] = (__bf16)W1[(size_t)(k0 + j) * HID + n];
        *(bf16x8*)(W1P + (size_t)t * 8) = v;
    } else {
        int i = t - 8192;
        if (i < HID) {
            int w = i >> 6, r = (i >> 2) & 15, n = i & 3;
            W2H[i] = (_Float16)W2[w * 64 + n * 16 + r];   // permuted
        }
    }
}

// ---------------- Kernel A: node projections (LDS-staged, fragment-order out) --
// P_src[n,:] = perm( h_src[n,:] @ W1[0:128,:] + b1 )   (blockIdx.y == 0)
// P_dst[n,:] = perm( h_dst[n,:] @ W1[128:256,:] )      (blockIdx.y == 1)
// Block: 64 nodes x 256 cols, 4 waves (wave tile 64 rows x 64 cols, acc[4][4]).
// Epilogue: zero shuffles — 2x cvt_pkrtz + one u64 store per (m,i); a 16-lane
// group writes 128B contiguous (full cache lines; fixes the 2x WRITE inflation).
__global__ __launch_bounds__(256) void k_proj(
    const float* __restrict__ hs, const float* __restrict__ hd,
    const __bf16* __restrict__ W1P, const float* __restrict__ b1,
    _Float16* __restrict__ Ps, _Float16* __restrict__ Pd, int NN)
{
    __shared__ __bf16 Atile[BM][LDA];

    const int which = blockIdx.y;
    const float* __restrict__ h = which ? hd : hs;
    _Float16* __restrict__ P = which ? Pd : Ps;

    const int lane  = threadIdx.x & 63;
    const int w     = threadIdx.x >> 6;   // wave 0..3 -> col group
    const int n0    = w * 64;
    const int node0 = blockIdx.x * BM;
    const int qr = lane & 15;
    const int qg = lane >> 4;
    const bf16x8* __restrict__ W1Pv = (const bf16x8*)W1P;

    // ---- stage A: 64 rows x 128 fp32 -> bf16 LDS; instr j covers 4KB coalesced.
    {
        const int t = threadIdx.x;
#pragma unroll
        for (int j = 0; j < 8; ++j) {
            int g   = t + 256 * j;        // 0..2047: 32 16B-chunks per row
            int row = g >> 5;
            int c4  = (g & 31) * 4;
            int rsrc = node0 + row; if (rsrc > NN - 1) rsrc = NN - 1;
            float4 f = *(const float4*)(h + (size_t)rsrc * IN_FEATS + c4);
            bf16x4 v = { (__bf16)f.x, (__bf16)f.y, (__bf16)f.z, (__bf16)f.w };
            *(bf16x4*)&Atile[row][c4] = v;
        }
    }
    __syncthreads();

    f32x4 acc[4][4];
#pragma unroll
    for (int m = 0; m < 4; ++m)
#pragma unroll
        for (int n = 0; n < 4; ++n) acc[m][n] = (f32x4){0.f, 0.f, 0.f, 0.f};

#pragma unroll
    for (int ks = 0; ks < 4; ++ks) {
        bf16x8 a[4];
#pragma unroll
        for (int m = 0; m < 4; ++m)
            a[m] = *(const bf16x8*)&Atile[m * 16 + qr][ks * 32 + qg * 8];
#pragma unroll
        for (int n = 0; n < 4; ++n) {
            bf16x8 b = W1Pv[((size_t)(which * 4 + ks) * 16 + w * 4 + n) * 64 + lane];
#pragma unroll
            for (int m = 0; m < 4; ++m)
                acc[m][n] = __builtin_amdgcn_mfma_f32_16x16x32_bf16(a[m], b, acc[m][n], 0, 0, 0);
        }
    }

    // ---- epilogue (fragment-native store). bias uses OLD col = n0+n*16+qr.
    float bias[4];
#pragma unroll
    for (int n = 0; n < 4; ++n)
        bias[n] = which ? 0.f : b1[n0 + n * 16 + qr];

#pragma unroll
    for (int m = 0; m < 4; ++m) {
#pragma unroll
        for (int i = 0; i < 4; ++i) {
            const int row = node0 + m * 16 + qg * 4 + i;
            if (row < NN) {
                auto p0 = __builtin_amdgcn_cvt_pkrtz(acc[m][0][i] + bias[0],
                                                     acc[m][1][i] + bias[1]);
                auto p1 = __builtin_amdgcn_cvt_pkrtz(acc[m][2][i] + bias[2],
                                                     acc[m][3][i] + bias[3]);
                uint2 wd = { __builtin_bit_cast(unsigned, p0),
                             __builtin_bit_cast(unsigned, p1) };
                *(uint2*)(P + (size_t)row * HID + n0 + qr * 4) = wd;
            }
        }
    }
}

// ---------------- Kernel B: edge scoring (fp16, v_dot2 path) -------------------
// score[e] = b2 + sum_j relu(Ps[src[e]][j] + Pd[dst[e]][j]) * W2H[j]  (both in
// the same permuted layout -> dot is order-invariant).
// Fabric-BW-bound (~3.5 TB/s L2-miss service on random lines) — structural.
__device__ __forceinline__ float dot8f(h8 a, h8 c, h8 w, float acc) {
    h8 r = a + c;                                        // 4x v_pk_add_f16
    r = __builtin_elementwise_max(r, (h8)(_Float16)0.f); // 4x v_pk_max_f16
#pragma unroll
    for (int j = 0; j < 4; ++j) {
        h2 p = {r[2 * j], r[2 * j + 1]};
        h2 q = {w[2 * j], w[2 * j + 1]};
        acc = __builtin_amdgcn_fdot2(p, q, acc, false);  // v_dot2_f32_f16
    }
    return acc;
}

__global__ __launch_bounds__(256) void k_edge(
    const _Float16* __restrict__ Ps, const _Float16* __restrict__ Pd,
    const int* __restrict__ src, const int* __restrict__ dst,
    const _Float16* __restrict__ W2H, const float* __restrict__ b2,
    float* __restrict__ out, int E)
{
    const int lane = threadIdx.x & 63;
    const int q = lane & 15;             // element slice
    const int g = lane >> 4;             // edge slot within wave
    const int wave = blockIdx.x * 4 + (threadIdx.x >> 6);
    const int nw = gridDim.x * 4;

    const h8* __restrict__ W2v = (const h8*)W2H;
    const h8 wa0 = W2v[q];          // permuted elems 8q..8q+7
    const h8 wa1 = W2v[16 + q];     // permuted elems 128+8q..
    const float bias = b2[0];

    for (int base = wave * 8; base < E; base += nw * 8) {
        const int e0 = base + g;
        const int e1 = base + 4 + g;
        const bool v0 = (e0 < E), v1 = (e1 < E);
        float acc0 = 0.f, acc1 = 0.f;
        if (v0) {
            const h8* ps = (const h8*)(Ps + (size_t)src[e0] * HID);
            const h8* pd = (const h8*)(Pd + (size_t)dst[e0] * HID);
            h8 a0 = ps[q], a1 = ps[16 + q], c0 = pd[q], c1 = pd[16 + q];
            if (v1) {
                const h8* ps1 = (const h8*)(Ps + (size_t)src[e1] * HID);
                const h8* pd1 = (const h8*)(Pd + (size_t)dst[e1] * HID);
                h8 b0 = ps1[q], b1v = ps1[16 + q], d0 = pd1[q], d1 = pd1[16 + q];
                acc0 = dot8f(a0, c0, wa0, acc0);
                acc0 = dot8f(a1, c1, wa1, acc0);
                acc1 = dot8f(b0, d0, wa0, acc1);
                acc1 = dot8f(b1v, d1, wa1, acc1);
            } else {
                acc0 = dot8f(a0, c0, wa0, acc0);
                acc0 = dot8f(a1, c1, wa1, acc0);
            }
        }
#pragma unroll
        for (int m = 1; m < 16; m <<= 1) {
            acc0 += __shfl_xor(acc0, m, 64);
            acc1 += __shfl_xor(acc1, m, 64);
        }
        if (q == 0) {
            if (v0) out[e0] = acc0 + bias;
            if (v1) out[e1] = acc1 + bias;
        }
    }
}

// ---------------- launch -------------------------------------------------------
extern "C" void kernel_launch(void* const* d_in, const int* in_sizes, int n_in,
                              void* d_out, int out_size, void* d_ws, size_t ws_size,
                              hipStream_t stream) {
    const float* h_src = (const float*)d_in[0];
    const float* h_dst = (const float*)d_in[1];
    const int*   src   = (const int*)d_in[2];
    const int*   dst   = (const int*)d_in[3];
    const float* W1    = (const float*)d_in[4];
    const float* b1    = (const float*)d_in[5];
    const float* W2    = (const float*)d_in[6];
    const float* b2    = (const float*)d_in[7];
    float* out = (float*)d_out;

    const int E  = in_sizes[2];
    const int NN = in_sizes[0] / IN_FEATS;   // 100000

    // ws layout: [W1P bf16 64K elems =128KB][W2H fp16 256][pad to 256KB][Ps fp16][Pd fp16]
    __bf16*    W1P = (__bf16*)d_ws;
    _Float16*  W2H = (_Float16*)((char*)d_ws + 131072);
    _Float16*  Ps  = (_Float16*)((char*)d_ws + 262144);
    _Float16*  Pd  = Ps + (size_t)NN * HID;

    k_prep<<<33, 256, 0, stream>>>(W1, W2, W1P, W2H);
    dim3 gA((NN + BM - 1) / BM, 2);
    k_proj<<<gA, 256, 0, stream>>>(h_src, h_dst, W1P, b1, Ps, Pd, NN);
    k_edge<<<2048, 256, 0, stream>>>(Ps, Pd, src, dst, W2H, b2, out, E);
}